// Round 4
// baseline (792.701 us; speedup 1.0000x reference)
//
#include <hip/hip_runtime.h>

#define NTOK 8192
#define CDIM 1024
#define ENUM 8
#define HDIM 4096

typedef unsigned short u16;
typedef unsigned int u32;
typedef __attribute__((ext_vector_type(8))) short s16x8;
typedef __attribute__((ext_vector_type(4))) float f32x4;

static __device__ __forceinline__ u16 f2bf(float f) {
  union { float f; u32 u; } v; v.f = f;
  u32 r = v.u + 0x7fffu + ((v.u >> 16) & 1u);
  return (u16)(r >> 16);
}
static __device__ __forceinline__ u32 pack2(float a, float b) {
  return (u32)f2bf(a) | ((u32)f2bf(b) << 16);
}
static __device__ __forceinline__ float bflo(u32 v) {
  union { u32 u; float f; } x; x.u = v << 16; return x.f;
}
static __device__ __forceinline__ float bfhi(u32 v) {
  union { u32 u; float f; } x; x.u = v & 0xffff0000u; return x.f;
}

typedef __attribute__((address_space(1))) const void gvoid;
typedef __attribute__((address_space(3))) void lvoid;
static __device__ __forceinline__ void gload16(const u16* g, u16* l) {
  __builtin_amdgcn_global_load_lds((gvoid*)g, (lvoid*)l, 16, 0, 0);
}

// gelu(x) ~= x * sigmoid(2*0.79788456*(x + 0.044715 x^3)); max dev ~1e-3 vs erf form
static __device__ __forceinline__ float gelu_fast(float v) {
  float u = v * (1.5957691216f + 0.1426929792f * v * v);
  return v / (1.f + __expf(-u));
}

// ---------------- weight convert + transpose: w[E][K][N] f32 -> wt[E][N][K] bf16 ----
__global__ void wconv_kernel(const float* __restrict__ w, u16* __restrict__ wt,
                             int K, int N) {
  __shared__ float lt[64][65];
  const int e = blockIdx.z, k0 = blockIdx.y * 64, n0 = blockIdx.x * 64;
  const float* src = w + (size_t)e * K * N;
  u16* dst = wt + (size_t)e * N * K;
  const int t = threadIdx.x;
  const int tr = t >> 4, tc = (t & 15) * 4;
#pragma unroll
  for (int i = 0; i < 4; ++i) {
    float4 v = *(const float4*)(src + (size_t)(k0 + tr + i * 16) * N + n0 + tc);
    lt[tr + i * 16][tc] = v.x; lt[tr + i * 16][tc + 1] = v.y;
    lt[tr + i * 16][tc + 2] = v.z; lt[tr + i * 16][tc + 3] = v.w;
  }
  __syncthreads();
#pragma unroll
  for (int i = 0; i < 4; ++i) {
    int n = tr + i * 16;
    uint2 o;
    o.x = pack2(lt[tc + 0][n], lt[tc + 1][n]);
    o.y = pack2(lt[tc + 2][n], lt[tc + 3][n]);
    *(uint2*)(dst + (size_t)(n0 + n) * K + k0 + tc) = o;
  }
}

// ---------------- gating ----------------
__global__ void gate_kernel(const float* __restrict__ x, const float* __restrict__ wg,
                            int* __restrict__ cnt, int* __restrict__ tok_e,
                            float* __restrict__ tok_w) {
  int gw = (blockIdx.x * blockDim.x + threadIdx.x) >> 6;
  int lane = threadIdx.x & 63;
  if (gw >= NTOK) return;
  const float* xr = x + (size_t)gw * CDIM;
  float acc[ENUM];
#pragma unroll
  for (int e = 0; e < ENUM; ++e) acc[e] = 0.f;
  for (int i = 0; i < CDIM / 64; ++i) {
    int c = i * 64 + lane;
    float xv = xr[c];
    float4 wa = *(const float4*)(wg + (size_t)c * ENUM);
    float4 wb = *(const float4*)(wg + (size_t)c * ENUM + 4);
    acc[0] += xv * wa.x; acc[1] += xv * wa.y; acc[2] += xv * wa.z; acc[3] += xv * wa.w;
    acc[4] += xv * wb.x; acc[5] += xv * wb.y; acc[6] += xv * wb.z; acc[7] += xv * wb.w;
  }
#pragma unroll
  for (int e = 0; e < ENUM; ++e) {
#pragma unroll
    for (int off = 32; off > 0; off >>= 1) acc[e] += __shfl_xor(acc[e], off);
  }
  if (lane == 0) {
    int i0 = 0; float v0 = acc[0];
#pragma unroll
    for (int e = 1; e < ENUM; ++e) if (acc[e] > v0) { v0 = acc[e]; i0 = e; }
    int i1 = -1; float v1 = -3.4e38f;
#pragma unroll
    for (int e = 0; e < ENUM; ++e) if (e != i0 && acc[e] > v1) { v1 = acc[e]; i1 = e; }
    float ex = expf(v1 - v0);
    float den = 1.f + ex;
    tok_e[gw * 2] = i0;     tok_w[gw * 2] = 1.f / den;
    tok_e[gw * 2 + 1] = i1; tok_w[gw * 2 + 1] = ex / den;
    atomicAdd(&cnt[i0], 1); atomicAdd(&cnt[i1], 1);
  }
}

__global__ void offsets_kernel(const int* __restrict__ cnt, int* __restrict__ offs) {
  if (threadIdx.x == 0 && blockIdx.x == 0) {
    int s = 0;
    for (int e = 0; e < ENUM; ++e) { offs[e] = s; s += cnt[e]; }
  }
}

__global__ void assign_kernel(const int* __restrict__ tok_e, const int* __restrict__ offs,
                              int* __restrict__ fill, int* __restrict__ slot_tok,
                              int* __restrict__ tok_slot) {
  int n = blockIdx.x * blockDim.x + threadIdx.x;
  if (n >= NTOK) return;
#pragma unroll
  for (int j = 0; j < 2; ++j) {
    int e = tok_e[n * 2 + j];
    int pos = atomicAdd(&fill[e], 1);
    int slot = offs[e] + pos;
    slot_tok[slot] = n;
    tok_slot[n * 2 + j] = slot;
  }
}

// gather routed rows of x into packed bf16 matrix xg [2N][C]
__global__ void gather_kernel(const float* __restrict__ x, const int* __restrict__ slot_tok,
                              u16* __restrict__ xg) {
  int gid = blockIdx.x * blockDim.x + threadIdx.x;
  int slot = gid >> 8;
  int c4 = (gid & 255) * 4;
  int tok = slot_tok[slot];
  float4 v = *(const float4*)(x + (size_t)tok * CDIM + c4);
  uint2 o; o.x = pack2(v.x, v.y); o.y = pack2(v.z, v.w);
  *(uint2*)(xg + (size_t)slot * CDIM + c4) = o;
}

// ---------------- expert GEMMs: 256x256 tile, BK=32, 4-deep LDS pipeline ----------
// A: bf16 [slots][K]; B^T: bf16 [E][N][K]. 8 waves (2M x 4N), per-wave 128x64 out.
// LDS: 4 buffers x (A 16KB + B 16KB) = 128 KB. Swizzle: oct ^= (row>>1)&3, applied
// on the global source (linear gload_lds dest) and on ds_read addresses.
// Pipeline: phase t: stage K-tile t+3, ds_read frags of t+1, MFMA on t,
//           s_waitcnt vmcnt(4) (retire t+2), s_barrier. Never drains mid-loop.
template <int PHASE, int KK, int NN, int NTI>
__global__ __launch_bounds__(512, 2) void moe_gemm(
    const u16* __restrict__ Ag, const u16* __restrict__ Bt, const float* __restrict__ bias,
    u16* __restrict__ outp,
    const int* __restrict__ cnts, const int* __restrict__ offs) {
  // block swizzle: per-expert 64*NTI blocks; first 8*NTI (mt<8, common case) are
  // XCD-chunked; remainder (rare overflow mt>=8) linear.
  const int per_e = 64 * NTI;
  const int e = blockIdx.x / per_e;
  const int r = blockIdx.x % per_e;
  int mt, nt;
  if (r < 8 * NTI) {
    const int chunk = r & 7, inner = r >> 3;
    if (NTI == 16) {  // (R,C)=(2,4): chunk = (mt>>2)*4 + (nt>>2), inner=(mt&3)*4+(nt&3)
      mt = ((chunk >> 2) << 2) | (inner >> 2);
      nt = ((chunk & 3) << 2) | (inner & 3);
    } else {          // NTI==4, (R,C)=(4,2)
      mt = ((chunk >> 1) << 1) | (inner >> 1);
      nt = ((chunk & 1) << 1) | (inner & 1);
    }
  } else {
    const int rr = r - 8 * NTI;
    mt = 8 + rr / NTI;
    nt = rr % NTI;
  }
  const int cnt = cnts[e];
  if (mt * 256 >= cnt) return;
  const int moff = offs[e];

  const int tid = threadIdx.x;
  const int wv = tid >> 6, ln = tid & 63;
  const int lr = ln & 15, lg = ln >> 4;
  const int wm = wv >> 2, wn = wv & 3;

  __shared__ __align__(16) u16 lds[4][2][8192];  // 128 KB

  const u16* Abase = Ag + (size_t)moff * KK;
  const u16* Bbase = Bt + (size_t)e * NN * KK + (size_t)nt * 256 * KK;

  // staging geometry (per wave: 2 A-loads + 2 B-loads per K-tile)
  const int r0 = wv * 32 + (ln >> 2);                 // rows r0, r0+16
  const int so = (((ln & 3) ^ ((ln >> 3) & 3))) * 8;  // swizzled source k-octet offset
  int ra0 = mt * 256 + r0;      ra0 = ra0 < cnt ? ra0 : cnt - 1;
  int ra1 = mt * 256 + r0 + 16; ra1 = ra1 < cnt ? ra1 : cnt - 1;
  const size_t aoff0 = (size_t)ra0 * KK + so;
  const size_t aoff1 = (size_t)ra1 * KK + so;
  const size_t boff0 = (size_t)r0 * KK + so;
  const size_t boff1 = (size_t)(r0 + 16) * KK + so;

  auto STAGE = [&](int kt) {
    const int p = kt & 3;
    u16* dA = &lds[p][0][0] + wv * 1024;
    u16* dB = &lds[p][1][0] + wv * 1024;
    const size_t kb = (size_t)kt * 32;
    gload16(Abase + aoff0 + kb, dA);
    gload16(Abase + aoff1 + kb, dA + 512);
    gload16(Bbase + boff0 + kb, dB);
    gload16(Bbase + boff1 + kb, dB + 512);
  };

  // frag read addressing (swizzle on read side)
  const int sw = lg ^ ((lr >> 1) & 3);
  s16x8 fa0[8], fb0[4], fa1[8], fb1[4];
  auto LOADFRAGS = [&](s16x8 (&fa)[8], s16x8 (&fb)[4], int p) {
    const u16* bufA = &lds[p][0][0];
    const u16* bufB = &lds[p][1][0];
#pragma unroll
    for (int m = 0; m < 8; ++m)
      fa[m] = *(const s16x8*)(bufA + (wm * 128 + m * 16 + lr) * 32 + sw * 8);
#pragma unroll
    for (int n = 0; n < 4; ++n)
      fb[n] = *(const s16x8*)(bufB + (wn * 64 + n * 16 + lr) * 32 + sw * 8);
  };

  f32x4 acc[8][4];
#pragma unroll
  for (int m = 0; m < 8; ++m)
#pragma unroll
    for (int n = 0; n < 4; ++n) {
      acc[m][n][0] = 0.f; acc[m][n][1] = 0.f; acc[m][n][2] = 0.f; acc[m][n][3] = 0.f;
    }

  const int nk = KK / 32;  // even (32 or 128)

  // prologue: stage K0..K2, wait K0+K1, read K0 frags
  STAGE(0); STAGE(1); STAGE(2);
  asm volatile("s_waitcnt vmcnt(4)" ::: "memory");
  __builtin_amdgcn_sched_barrier(0);
  __builtin_amdgcn_s_barrier();
  __builtin_amdgcn_sched_barrier(0);
  LOADFRAGS(fa0, fb0, 0);

#define MFMA_ALL(FA, FB)                                                            \
  _Pragma("unroll")                                                                 \
  for (int m = 0; m < 8; ++m)                                                       \
    _Pragma("unroll")                                                               \
    for (int n = 0; n < 4; ++n)                                                     \
      acc[m][n] = __builtin_amdgcn_mfma_f32_16x16x32_bf16(FA[m], FB[n], acc[m][n], 0, 0, 0);

#define PHASE_END()                                        \
  asm volatile("s_waitcnt vmcnt(4)" ::: "memory");         \
  __builtin_amdgcn_sched_barrier(0);                       \
  __builtin_amdgcn_s_barrier();                            \
  __builtin_amdgcn_sched_barrier(0);

  for (int t = 0; t < nk; t += 2) {
    // phase t: cur = set0, nxt = set1
    if (t + 3 < nk) STAGE(t + 3);
    LOADFRAGS(fa1, fb1, (t + 1) & 3);
    __builtin_amdgcn_s_setprio(1);
    MFMA_ALL(fa0, fb0);
    __builtin_amdgcn_s_setprio(0);
    PHASE_END();
    // phase t+1: cur = set1, nxt = set0
    if (t + 4 < nk) STAGE(t + 4);
    LOADFRAGS(fa0, fb0, (t + 2) & 3);
    __builtin_amdgcn_s_setprio(1);
    MFMA_ALL(fa1, fb1);
    __builtin_amdgcn_s_setprio(0);
    PHASE_END();
  }

  asm volatile("s_waitcnt vmcnt(0) lgkmcnt(0)" ::: "memory");
  __builtin_amdgcn_sched_barrier(0);
  __syncthreads();

  // epilogue: bias (+gelu), repack bf16 via LDS, coalesced uint4 stores
  u16* lT = &lds[0][0][0];  // 256x256 bf16 = 128 KB
  float bv[4];
#pragma unroll
  for (int n = 0; n < 4; ++n)
    bv[n] = bias[(size_t)e * NN + nt * 256 + wn * 64 + n * 16 + lr];
#pragma unroll
  for (int m = 0; m < 8; ++m) {
#pragma unroll
    for (int r4 = 0; r4 < 4; ++r4) {
      int row = wm * 128 + m * 16 + lg * 4 + r4;
#pragma unroll
      for (int n = 0; n < 4; ++n) {
        int col = wn * 64 + n * 16 + lr;
        float v = acc[m][n][r4] + bv[n];
        if (PHASE == 1) v = gelu_fast(v);
        lT[row * 256 + col] = f2bf(v);
      }
    }
  }
  __syncthreads();
#pragma unroll
  for (int j = 0; j < 16; ++j) {
    int idx = j * 512 + tid;       // uint4 index; 8192 total
    int row = idx >> 5;            // 32 uint4 per row
    int cu = idx & 31;
    int grow = mt * 256 + row;
    if (grow < cnt) {
      uint4 v = ((const uint4*)lT)[idx];
      *(uint4*)(outp + (size_t)(moff + grow) * NN + nt * 256 + cu * 8) = v;
    }
  }
#undef MFMA_ALL
#undef PHASE_END
}

// out[tok] = w0 * y[slot0] + w1 * y[slot1]
__global__ void combine_kernel(const u16* __restrict__ y, const int* __restrict__ tok_slot,
                               const float* __restrict__ tok_w, float* __restrict__ out) {
  int gid = blockIdx.x * blockDim.x + threadIdx.x;
  int n = gid >> 8;
  int c4 = (gid & 255) * 4;
  int s0 = tok_slot[n * 2], s1 = tok_slot[n * 2 + 1];
  float w0 = tok_w[n * 2], w1 = tok_w[n * 2 + 1];
  uint2 a = *(const uint2*)(y + (size_t)s0 * CDIM + c4);
  uint2 b = *(const uint2*)(y + (size_t)s1 * CDIM + c4);
  float4 o;
  o.x = w0 * bflo(a.x) + w1 * bflo(b.x);
  o.y = w0 * bfhi(a.x) + w1 * bfhi(b.x);
  o.z = w0 * bflo(a.y) + w1 * bflo(b.y);
  o.w = w0 * bfhi(a.y) + w1 * bfhi(b.y);
  *(float4*)(out + (size_t)n * CDIM + c4) = o;
}

extern "C" void kernel_launch(void* const* d_in, const int* in_sizes, int n_in,
                              void* d_out, int out_size, void* d_ws, size_t ws_size,
                              hipStream_t stream) {
  const float* x  = (const float*)d_in[0];
  const float* wg = (const float*)d_in[1];
  const float* w1 = (const float*)d_in[2];
  const float* b1 = (const float*)d_in[3];
  const float* w2 = (const float*)d_in[4];
  const float* b2 = (const float*)d_in[5];
  float* out = (float*)d_out;

  char* ws = (char*)d_ws;
  int* cnt  = (int*)ws;
  int* fill = cnt + 8;
  int* offs = cnt + 16;
  size_t off = 256;
  int*   tok_e    = (int*)(ws + off);   off += (size_t)NTOK * 2 * 4;
  float* tok_w    = (float*)(ws + off); off += (size_t)NTOK * 2 * 4;
  int*   slot_tok = (int*)(ws + off);   off += (size_t)NTOK * 2 * 4;
  int*   tok_slot = (int*)(ws + off);   off += (size_t)NTOK * 2 * 4;
  u16*   xg  = (u16*)(ws + off); off += (size_t)NTOK * 2 * CDIM * 2;
  u16*   h   = (u16*)(ws + off); off += (size_t)NTOK * 2 * HDIM * 2;
  u16*   y   = (u16*)(ws + off); off += (size_t)NTOK * 2 * CDIM * 2;
  u16*   w1t = (u16*)(ws + off); off += (size_t)ENUM * CDIM * HDIM * 2;
  u16*   w2t = (u16*)(ws + off); off += (size_t)ENUM * HDIM * CDIM * 2;

  hipMemsetAsync(cnt, 0, 64, stream);

  wconv_kernel<<<dim3(HDIM / 64, CDIM / 64, ENUM), 256, 0, stream>>>(w1, w1t, CDIM, HDIM);
  wconv_kernel<<<dim3(CDIM / 64, HDIM / 64, ENUM), 256, 0, stream>>>(w2, w2t, HDIM, CDIM);

  gate_kernel<<<NTOK / 4, 256, 0, stream>>>(x, wg, cnt, tok_e, tok_w);
  offsets_kernel<<<1, 64, 0, stream>>>(cnt, offs);
  assign_kernel<<<NTOK / 256, 256, 0, stream>>>(tok_e, offs, fill, slot_tok, tok_slot);
  gather_kernel<<<NTOK * 2, 256, 0, stream>>>(x, slot_tok, xg);

  moe_gemm<1, CDIM, HDIM, 16><<<ENUM * 64 * 16, 512, 0, stream>>>(
      xg, w1t, b1, h, cnt, offs);
  moe_gemm<2, HDIM, CDIM, 4><<<ENUM * 64 * 4, 512, 0, stream>>>(
      h, w2t, b2, y, cnt, offs);

  combine_kernel<<<NTOK, 256, 0, stream>>>(y, tok_slot, tok_w, out);
}